// Round 1
// baseline (66896.271 us; speedup 1.0000x reference)
//
#include <hip/hip_runtime.h>
#include <cmath>

// Problem constants
#define T_STEPS 16384
#define D_IN    257
#define H_DIM   512
#define O_DIM   257
#define G4      2048   // 4*H

// Workspace layout (bytes):
//   [0)          : unsigned int counter
//   [256)        : float h_buf[2][512]   (double-buffered h broadcast)
//   [8192)       : float x_gates[T][2048]
//   [8192+T*2048*4) : float hs[T][512]
#define WS_HBUF_OFF   256
#define WS_XG_OFF     8192
#define WS_HS_OFF     (8192 + (size_t)T_STEPS * G4 * 4)

// ---------------------------------------------------------------------------
// Phase 1: x_gates[t][j] = sum_k stft[t][k] * W_ih[j][k] + (b_ih[j]+b_hh[j])
// 64x64 tile per 256-thread block, 4x4 micro-tile, K-chunks of 16 in LDS.
// ---------------------------------------------------------------------------
__global__ __launch_bounds__(256) void xgate_gemm(
    const float* __restrict__ stft, const float* __restrict__ W_ih,
    const float* __restrict__ b_ih, const float* __restrict__ b_hh,
    float* __restrict__ xg)
{
    const int tid = threadIdx.x;
    const int tx = tid & 15, ty = tid >> 4;
    const int j0 = blockIdx.x * 64;
    const int t0 = blockIdx.y * 64;

    __shared__ float s_a[64][17];  // stft tile  [t][k]
    __shared__ float s_b[64][17];  // W_ih tile  [j][k]

    float acc[4][4] = {};

    for (int k0 = 0; k0 < D_IN; k0 += 16) {
        #pragma unroll
        for (int l = 0; l < 4; ++l) {
            int idx = tid + l * 256;       // 0..1023
            int r  = idx >> 4;
            int kk = idx & 15;
            int k  = k0 + kk;
            s_a[r][kk] = (k < D_IN) ? stft[(size_t)(t0 + r) * D_IN + k] : 0.f;
            s_b[r][kk] = (k < D_IN) ? W_ih[(size_t)(j0 + r) * D_IN + k] : 0.f;
        }
        __syncthreads();
        #pragma unroll
        for (int kk = 0; kk < 16; ++kk) {
            float a[4], b[4];
            #pragma unroll
            for (int r = 0; r < 4; ++r) a[r] = s_a[ty * 4 + r][kk];
            #pragma unroll
            for (int c = 0; c < 4; ++c) b[c] = s_b[tx * 4 + c][kk];
            #pragma unroll
            for (int r = 0; r < 4; ++r)
                #pragma unroll
                for (int c = 0; c < 4; ++c)
                    acc[r][c] += a[r] * b[c];
        }
        __syncthreads();
    }

    float bias[4];
    #pragma unroll
    for (int c = 0; c < 4; ++c) {
        int j = j0 + tx * 4 + c;
        bias[c] = b_ih[j] + b_hh[j];
    }
    #pragma unroll
    for (int r = 0; r < 4; ++r) {
        int t = t0 + ty * 4 + r;
        #pragma unroll
        for (int c = 0; c < 4; ++c) {
            xg[(size_t)t * G4 + j0 + tx * 4 + c] = acc[r][c] + bias[c];
        }
    }
}

// ---------------------------------------------------------------------------
// Phase 2: persistent sequential LSTM.
// 32 blocks x 256 threads. Block g owns h-indices [16g,16g+16) -> 64 W_hh rows
// (i,f,g,o gates), held in VGPRs (128 floats/thread).
// Per-step sync: agent-scope monotonic counter; h via double-buffered global.
// ---------------------------------------------------------------------------
__global__ __launch_bounds__(256) void lstm_seq(
    const float* __restrict__ W_hh, const float* __restrict__ xg,
    float* __restrict__ hs, float* h_buf, unsigned int* cnt)
{
    const int tid = threadIdx.x;
    const int g   = blockIdx.x;          // 0..31
    const int rl  = tid & 63;            // local row: gate*16 + jj
    const int q   = tid >> 6;            // col chunk 0..3 (128 cols each)
    const int grow = (rl >> 4) * H_DIM + g * 16 + (rl & 15);  // global W_hh row

    // Load this thread's 128 weights into registers.
    float4 wv[32];
    {
        const float4* wrow = (const float4*)(W_hh + (size_t)grow * H_DIM + q * 128);
        #pragma unroll
        for (int i = 0; i < 32; ++i) wv[i] = wrow[i];
    }

    __shared__ float s_h[H_DIM];
    __shared__ float s_part[64 * 5];   // [rl][q], pitch 5 to spread banks
    __shared__ float s_gates[64];

    float c_state = 0.f;               // valid for tid < 16

    for (int t = 0; t < T_STEPS; ++t) {
        const int buf = t & 1;

        // Prefetch x_gates (independent of h) before the spin.
        float xg_v = 0.f;
        if (tid < 64) xg_v = xg[(size_t)t * G4 + grow];

        // Wait until all 32 blocks have published h for step t.
        if (tid == 0) {
            const unsigned int target = 32u * (unsigned int)t;
            while (__hip_atomic_load(cnt, __ATOMIC_ACQUIRE,
                                     __HIP_MEMORY_SCOPE_AGENT) < target) { }
        }
        __syncthreads();

        // Stage h into LDS (agent-scope loads bypass stale caches).
        s_h[tid] = __hip_atomic_load(&h_buf[buf * H_DIM + tid],
                                     __ATOMIC_RELAXED, __HIP_MEMORY_SCOPE_AGENT);
        s_h[tid + 256] = __hip_atomic_load(&h_buf[buf * H_DIM + tid + 256],
                                     __ATOMIC_RELAXED, __HIP_MEMORY_SCOPE_AGENT);
        __syncthreads();

        // Matvec partial: this thread's 128-col slice of its row.
        const float4* hv = (const float4*)(s_h + q * 128);
        float acc = 0.f;
        #pragma unroll
        for (int i = 0; i < 32; ++i) {
            float4 h4 = hv[i];
            acc += wv[i].x * h4.x + wv[i].y * h4.y +
                   wv[i].z * h4.z + wv[i].w * h4.w;
        }
        s_part[rl * 5 + q] = acc;
        __syncthreads();

        if (tid < 64) {
            s_gates[tid] = xg_v + s_part[tid * 5 + 0] + s_part[tid * 5 + 1]
                                + s_part[tid * 5 + 2] + s_part[tid * 5 + 3];
        }
        __syncthreads();

        if (tid < 16) {
            float iv = s_gates[tid];
            float fv = s_gates[16 + tid];
            float gv = s_gates[32 + tid];
            float ov = s_gates[48 + tid];
            iv = 1.f / (1.f + expf(-iv));
            fv = 1.f / (1.f + expf(-fv));
            ov = 1.f / (1.f + expf(-ov));
            gv = tanhf(gv);
            c_state = fv * c_state + iv * gv;
            float h_new = ov * tanhf(c_state);
            hs[(size_t)t * H_DIM + g * 16 + tid] = h_new;
            __hip_atomic_store(&h_buf[(buf ^ 1) * H_DIM + g * 16 + tid], h_new,
                               __ATOMIC_RELAXED, __HIP_MEMORY_SCOPE_AGENT);
        }
        __syncthreads();   // drains vmcnt: slice stores are globally visible

        if (tid == 0) {
            __hip_atomic_fetch_add(cnt, 1u, __ATOMIC_RELEASE,
                                   __HIP_MEMORY_SCOPE_AGENT);
        }
    }
}

// ---------------------------------------------------------------------------
// Phase 3: out = log_softmax(hs @ W_out^T + b_out)
// One block per 16 t-rows; K-chunks of 32 in LDS; col 256 handled by tid<16.
// ---------------------------------------------------------------------------
__global__ __launch_bounds__(256) void out_softmax(
    const float* __restrict__ hs, const float* __restrict__ W_out,
    const float* __restrict__ b_out, float* __restrict__ out)
{
    const int tid = threadIdx.x;
    const int t0  = blockIdx.x * 16;

    __shared__ float s_w[257 * 33];
    __shared__ float s_hs[16 * 33];
    __shared__ float s_o[16 * 257];
    __shared__ float s_red[8];

    float acc[16] = {};
    float acc256 = 0.f;

    for (int k0 = 0; k0 < H_DIM; k0 += 32) {
        for (int idx = tid; idx < 257 * 32; idx += 256) {
            int row = idx >> 5, col = idx & 31;
            s_w[row * 33 + col] = W_out[(size_t)row * H_DIM + k0 + col];
        }
        for (int idx = tid; idx < 16 * 32; idx += 256) {
            int row = idx >> 5, col = idx & 31;
            s_hs[row * 33 + col] = hs[(size_t)(t0 + row) * H_DIM + k0 + col];
        }
        __syncthreads();
        #pragma unroll
        for (int kk = 0; kk < 32; ++kk) {
            float w = s_w[tid * 33 + kk];
            #pragma unroll
            for (int r = 0; r < 16; ++r)
                acc[r] += s_hs[r * 33 + kk] * w;
        }
        if (tid < 16) {
            #pragma unroll
            for (int kk = 0; kk < 32; ++kk)
                acc256 += s_w[256 * 33 + kk] * s_hs[tid * 33 + kk];
        }
        __syncthreads();
    }

    float bias_c = b_out[tid];
    #pragma unroll
    for (int r = 0; r < 16; ++r) s_o[r * 257 + tid] = acc[r] + bias_c;
    if (tid < 16) s_o[tid * 257 + 256] = acc256 + b_out[256];
    __syncthreads();

    const int lane = tid & 63, wid = tid >> 6;
    for (int r = 0; r < 16; ++r) {
        float v  = s_o[r * 257 + tid];
        float vx = (tid == 0) ? s_o[r * 257 + 256] : -INFINITY;
        float m = fmaxf(v, vx);
        #pragma unroll
        for (int off = 32; off > 0; off >>= 1) m = fmaxf(m, __shfl_xor(m, off, 64));
        if (lane == 0) s_red[wid] = m;
        __syncthreads();
        m = fmaxf(fmaxf(s_red[0], s_red[1]), fmaxf(s_red[2], s_red[3]));
        float e = expf(v - m) + ((tid == 0) ? expf(vx - m) : 0.f);
        #pragma unroll
        for (int off = 32; off > 0; off >>= 1) e += __shfl_xor(e, off, 64);
        if (lane == 0) s_red[4 + wid] = e;
        __syncthreads();
        float s = s_red[4] + s_red[5] + s_red[6] + s_red[7];
        float lg = logf(s) + m;
        out[(size_t)(t0 + r) * O_DIM + tid] = v - lg;
        if (tid == 0) out[(size_t)(t0 + r) * O_DIM + 256] = vx - lg;
    }
}

// ---------------------------------------------------------------------------
extern "C" void kernel_launch(void* const* d_in, const int* in_sizes, int n_in,
                              void* d_out, int out_size, void* d_ws, size_t ws_size,
                              hipStream_t stream) {
    (void)in_sizes; (void)n_in; (void)out_size; (void)ws_size;

    const float* stft  = (const float*)d_in[0];
    const float* W_ih  = (const float*)d_in[1];
    const float* W_hh  = (const float*)d_in[2];
    const float* b_ih  = (const float*)d_in[3];
    const float* b_hh  = (const float*)d_in[4];
    const float* W_out = (const float*)d_in[5];
    const float* b_out = (const float*)d_in[6];
    float* out = (float*)d_out;

    char* ws = (char*)d_ws;
    unsigned int* cnt = (unsigned int*)ws;
    float* h_buf = (float*)(ws + WS_HBUF_OFF);
    float* xg    = (float*)(ws + WS_XG_OFF);
    float* hs    = (float*)(ws + WS_HS_OFF);

    // Zero counter + h_buf (workspace is poisoned to 0xAA before every launch).
    hipMemsetAsync(ws, 0, 8192, stream);

    xgate_gemm<<<dim3(G4 / 64, T_STEPS / 64), 256, 0, stream>>>(
        stft, W_ih, b_ih, b_hh, xg);
    lstm_seq<<<32, 256, 0, stream>>>(W_hh, xg, hs, h_buf, cnt);
    out_softmax<<<T_STEPS / 16, 256, 0, stream>>>(hs, W_out, b_out, out);
}

// Round 4
// 34438.641 us; speedup vs baseline: 1.9425x; 1.9425x over previous
//
#include <hip/hip_runtime.h>
#include <cmath>

// Problem constants
#define T_STEPS 16384
#define D_IN    257
#define H_DIM   512
#define O_DIM   257
#define G4      2048   // 4*H

typedef unsigned long long u64;

// Workspace layout (bytes):
//   [0, 8192)    : u64 msg[2][512]  (double-buffered self-validating h msgs)
//                  msg word i = (tag << 32) | float_bits(h[i])
//   [8192, ...)  : float x_gates[T][2048]
//   then         : float hs[T][512]
#define WS_XG_OFF     8192
#define WS_HS_OFF     (8192 + (size_t)T_STEPS * G4 * 4)

__device__ inline float fast_sigmoid(float x) {
    return 1.f / (1.f + __expf(-x));
}
__device__ inline float fast_tanh(float x) {
    float ax = fminf(fabsf(x), 15.f);
    float e  = __expf(2.f * ax);
    float t  = (e - 1.f) / (e + 1.f);
    return copysignf(t, x);
}

// ---------------------------------------------------------------------------
// Phase 1: x_gates[t][j] = sum_k stft[t][k] * W_ih[j][k] + (b_ih[j]+b_hh[j])
// ---------------------------------------------------------------------------
__global__ __launch_bounds__(256) void xgate_gemm(
    const float* __restrict__ stft, const float* __restrict__ W_ih,
    const float* __restrict__ b_ih, const float* __restrict__ b_hh,
    float* __restrict__ xg)
{
    const int tid = threadIdx.x;
    const int tx = tid & 15, ty = tid >> 4;
    const int j0 = blockIdx.x * 64;
    const int t0 = blockIdx.y * 64;

    __shared__ float s_a[64][17];
    __shared__ float s_b[64][17];

    float acc[4][4] = {};

    for (int k0 = 0; k0 < D_IN; k0 += 16) {
        #pragma unroll
        for (int l = 0; l < 4; ++l) {
            int idx = tid + l * 256;
            int r  = idx >> 4;
            int kk = idx & 15;
            int k  = k0 + kk;
            s_a[r][kk] = (k < D_IN) ? stft[(size_t)(t0 + r) * D_IN + k] : 0.f;
            s_b[r][kk] = (k < D_IN) ? W_ih[(size_t)(j0 + r) * D_IN + k] : 0.f;
        }
        __syncthreads();
        #pragma unroll
        for (int kk = 0; kk < 16; ++kk) {
            float a[4], b[4];
            #pragma unroll
            for (int r = 0; r < 4; ++r) a[r] = s_a[ty * 4 + r][kk];
            #pragma unroll
            for (int c = 0; c < 4; ++c) b[c] = s_b[tx * 4 + c][kk];
            #pragma unroll
            for (int r = 0; r < 4; ++r)
                #pragma unroll
                for (int c = 0; c < 4; ++c)
                    acc[r][c] += a[r] * b[c];
        }
        __syncthreads();
    }

    float bias[4];
    #pragma unroll
    for (int c = 0; c < 4; ++c) {
        int j = j0 + tx * 4 + c;
        bias[c] = b_ih[j] + b_hh[j];
    }
    #pragma unroll
    for (int r = 0; r < 4; ++r) {
        int t = t0 + ty * 4 + r;
        #pragma unroll
        for (int c = 0; c < 4; ++c) {
            xg[(size_t)t * G4 + j0 + tx * 4 + c] = acc[r][c] + bias[c];
        }
    }
}

// ---------------------------------------------------------------------------
// Phase 2: persistent sequential LSTM, self-validating message sync.
// 32 blocks x 256 threads. Block g owns h[16g..16g+16) -> 64 W_hh rows.
// Thread layout: j = tid>>4 (h index in block), sub = tid&15,
//                gate = sub>>2, q = sub&3 (128-col slice).
// All partials + gates of one h-index live in one 16-lane group of one wave.
// Sync: 8B agent-scope atomic words carrying (tag<<32)|h_bits — observe and
// data arrive in the same load; no central counter, no fences.
// ---------------------------------------------------------------------------
__global__ __launch_bounds__(256, 1) void lstm_seq(
    const float* __restrict__ W_hh, const float* __restrict__ xg,
    float* __restrict__ hs, u64* msg)
{
    const int tid  = threadIdx.x;
    const int g    = blockIdx.x;          // 0..31
    const int j    = tid >> 4;            // 0..15
    const int sub  = tid & 15;
    const int gate = sub >> 2;            // 0..3
    const int q    = sub & 3;             // 0..3 (128-col chunk)
    const int lane = tid & 63;
    const int base = lane & 48;           // group base lane within wave
    const int row  = gate * H_DIM + g * 16 + j;

    // This thread's 128 weights in VGPRs/AGPRs.
    float4 wv[32];
    {
        const float4* wr = (const float4*)(W_hh + (size_t)row * H_DIM + q * 128);
        #pragma unroll
        for (int i = 0; i < 32; ++i) wv[i] = wr[i];
    }

    // Padded h: block q at q*132 words -> conflict-free 4-address broadcast.
    __shared__ float s_h[4 * 132];

    u64* slot0 = msg;
    u64* slot1 = msg + 512;

    float c_state = 0.f;                  // replicated across the 16-lane group

    const int c0 = 2 * tid;               // h columns this thread delivers
    const int pa = (c0 >> 7) * 132 + (c0 & 127);

    for (int t = 0; t < T_STEPS; ++t) {
        // Prefetch x_gate (independent of h) before the spin.
        float xv = 0.f;
        if (q == 0) xv = xg[(size_t)t * G4 + row];

        // Poll own two message words: tag==t validates payload in-load.
        u64* rp = ((t & 1) ? slot1 : slot0) + c0;
        u64 u0, u1;
        const unsigned tagt = (unsigned)t;
        for (;;) {
            u0 = __hip_atomic_load(rp,     __ATOMIC_RELAXED, __HIP_MEMORY_SCOPE_AGENT);
            u1 = __hip_atomic_load(rp + 1, __ATOMIC_RELAXED, __HIP_MEMORY_SCOPE_AGENT);
            if ((unsigned)(u0 >> 32) == tagt && (unsigned)(u1 >> 32) == tagt) break;
        }

        // Stage h into LDS (each thread owns 2 words; padded layout).
        s_h[pa]     = __uint_as_float((unsigned)u0);
        s_h[pa + 1] = __uint_as_float((unsigned)u1);
        __syncthreads();

        // Matvec: 128-col slice of this thread's row.
        const float4* hv = (const float4*)(s_h + q * 132);
        float acc = xv;
        #pragma unroll
        for (int i = 0; i < 32; ++i) {
            float4 h4 = hv[i];
            acc += wv[i].x * h4.x + wv[i].y * h4.y +
                   wv[i].z * h4.z + wv[i].w * h4.w;
        }

        // Quad reduce (q=0..3 are adjacent lanes).
        acc += __shfl_xor(acc, 1, 64);
        acc += __shfl_xor(acc, 2, 64);

        // Gather the 4 gate sums for this group (all in-wave).
        float gi = __shfl(acc, base + 0,  64);
        float gf = __shfl(acc, base + 4,  64);
        float gg = __shfl(acc, base + 8,  64);
        float go = __shfl(acc, base + 12, 64);

        // Activation, replicated (bitwise identical) across the 16-lane group.
        float iv = fast_sigmoid(gi);
        float fv = fast_sigmoid(gf);
        float ov = fast_sigmoid(go);
        float gv = fast_tanh(gg);
        c_state = fv * c_state + iv * gv;
        float hn = ov * fast_tanh(c_state);

        if (sub == 0) {
            hs[(size_t)t * H_DIM + g * 16 + j] = hn;
            u64 m = ((u64)(unsigned)(t + 1) << 32) | (u64)__float_as_uint(hn);
            u64* wp = (((t + 1) & 1) ? slot1 : slot0) + (g * 16 + j);
            __hip_atomic_store(wp, m, __ATOMIC_RELAXED, __HIP_MEMORY_SCOPE_AGENT);
        }

        // All matvec LDS reads done before next iteration overwrites s_h.
        // Also guarantees: publish of t+1 happens only after EVERY thread in
        // this block consumed its t-messages (double-buffer safety).
        __syncthreads();
    }
}

// ---------------------------------------------------------------------------
// Phase 3: out = log_softmax(hs @ W_out^T + b_out)
// ---------------------------------------------------------------------------
__global__ __launch_bounds__(256) void out_softmax(
    const float* __restrict__ hs, const float* __restrict__ W_out,
    const float* __restrict__ b_out, float* __restrict__ out)
{
    const int tid = threadIdx.x;
    const int t0  = blockIdx.x * 16;

    __shared__ float s_w[257 * 33];
    __shared__ float s_hs[16 * 33];
    __shared__ float s_o[16 * 257];
    __shared__ float s_red[8];

    float acc[16] = {};
    float acc256 = 0.f;

    for (int k0 = 0; k0 < H_DIM; k0 += 32) {
        for (int idx = tid; idx < 257 * 32; idx += 256) {
            int row = idx >> 5, col = idx & 31;
            s_w[row * 33 + col] = W_out[(size_t)row * H_DIM + k0 + col];
        }
        for (int idx = tid; idx < 16 * 32; idx += 256) {
            int row = idx >> 5, col = idx & 31;
            s_hs[row * 33 + col] = hs[(size_t)(t0 + row) * H_DIM + k0 + col];
        }
        __syncthreads();
        #pragma unroll
        for (int kk = 0; kk < 32; ++kk) {
            float w = s_w[tid * 33 + kk];
            #pragma unroll
            for (int r = 0; r < 16; ++r)
                acc[r] += s_hs[r * 33 + kk] * w;
        }
        if (tid < 16) {
            #pragma unroll
            for (int kk = 0; kk < 32; ++kk)
                acc256 += s_w[256 * 33 + kk] * s_hs[tid * 33 + kk];
        }
        __syncthreads();
    }

    float bias_c = b_out[tid];
    #pragma unroll
    for (int r = 0; r < 16; ++r) s_o[r * 257 + tid] = acc[r] + bias_c;
    if (tid < 16) s_o[tid * 257 + 256] = acc256 + b_out[256];
    __syncthreads();

    const int lane = tid & 63, wid = tid >> 6;
    for (int r = 0; r < 16; ++r) {
        float v  = s_o[r * 257 + tid];
        float vx = (tid == 0) ? s_o[r * 257 + 256] : -INFINITY;
        float m = fmaxf(v, vx);
        #pragma unroll
        for (int off = 32; off > 0; off >>= 1) m = fmaxf(m, __shfl_xor(m, off, 64));
        if (lane == 0) s_red[wid] = m;
        __syncthreads();
        m = fmaxf(fmaxf(s_red[0], s_red[1]), fmaxf(s_red[2], s_red[3]));
        float e = expf(v - m) + ((tid == 0) ? expf(vx - m) : 0.f);
        #pragma unroll
        for (int off = 32; off > 0; off >>= 1) e += __shfl_xor(e, off, 64);
        if (lane == 0) s_red[4 + wid] = e;
        __syncthreads();
        float s = s_red[4] + s_red[5] + s_red[6] + s_red[7];
        float lg = logf(s) + m;
        out[(size_t)(t0 + r) * O_DIM + tid] = v - lg;
        if (tid == 0) out[(size_t)(t0 + r) * O_DIM + 256] = vx - lg;
    }
}

// ---------------------------------------------------------------------------
extern "C" void kernel_launch(void* const* d_in, const int* in_sizes, int n_in,
                              void* d_out, int out_size, void* d_ws, size_t ws_size,
                              hipStream_t stream) {
    (void)in_sizes; (void)n_in; (void)out_size; (void)ws_size;

    const float* stft  = (const float*)d_in[0];
    const float* W_ih  = (const float*)d_in[1];
    const float* W_hh  = (const float*)d_in[2];
    const float* b_ih  = (const float*)d_in[3];
    const float* b_hh  = (const float*)d_in[4];
    const float* W_out = (const float*)d_in[5];
    const float* b_out = (const float*)d_in[6];
    float* out = (float*)d_out;

    char* ws = (char*)d_ws;
    u64* msg  = (u64*)ws;
    float* xg = (float*)(ws + WS_XG_OFF);
    float* hs = (float*)(ws + WS_HS_OFF);

    // Zero both msg slots (ws is re-poisoned to 0xAA before every launch).
    // tag 0 + h 0 is exactly the t=0 initial state.
    (void)hipMemsetAsync(ws, 0, 8192, stream);

    xgate_gemm<<<dim3(G4 / 64, T_STEPS / 64), 256, 0, stream>>>(
        stft, W_ih, b_ih, b_hh, xg);
    lstm_seq<<<32, 256, 0, stream>>>(W_hh, xg, hs, msg);
    out_softmax<<<T_STEPS / 16, 256, 0, stream>>>(hs, W_out, b_out, out);
}

// Round 5
// 27308.685 us; speedup vs baseline: 2.4496x; 1.2611x over previous
//
#include <hip/hip_runtime.h>
#include <cmath>

// Problem constants
#define T_STEPS 16384
#define D_IN    257
#define H_DIM   512
#define O_DIM   257
#define G4      2048   // 4*H

typedef unsigned long long u64;

// Workspace layout (bytes):
//   [0, 8192)    : u64 msg[2][512]  (double-buffered self-validating h msgs)
//                  msg word i = (tag << 32) | float_bits(h[i])
//   [8192, ...)  : float x_gates[T][2048]
//   then         : float hs[T][512]
#define WS_XG_OFF     8192
#define WS_HS_OFF     (8192 + (size_t)T_STEPS * G4 * 4)

__device__ inline float fast_sigmoid(float x) {
    return 1.f / (1.f + __expf(-x));
}
__device__ inline float fast_tanh(float x) {
    float ax = fminf(fabsf(x), 15.f);
    float e  = __expf(2.f * ax);
    float t  = (e - 1.f) / (e + 1.f);
    return copysignf(t, x);
}

// ---------------------------------------------------------------------------
// Phase 1: x_gates[t][j] = sum_k stft[t][k] * W_ih[j][k] + (b_ih[j]+b_hh[j])
// ---------------------------------------------------------------------------
__global__ __launch_bounds__(256) void xgate_gemm(
    const float* __restrict__ stft, const float* __restrict__ W_ih,
    const float* __restrict__ b_ih, const float* __restrict__ b_hh,
    float* __restrict__ xg)
{
    const int tid = threadIdx.x;
    const int tx = tid & 15, ty = tid >> 4;
    const int j0 = blockIdx.x * 64;
    const int t0 = blockIdx.y * 64;

    __shared__ float s_a[64][17];
    __shared__ float s_b[64][17];

    float acc[4][4] = {};

    for (int k0 = 0; k0 < D_IN; k0 += 16) {
        #pragma unroll
        for (int l = 0; l < 4; ++l) {
            int idx = tid + l * 256;
            int r  = idx >> 4;
            int kk = idx & 15;
            int k  = k0 + kk;
            s_a[r][kk] = (k < D_IN) ? stft[(size_t)(t0 + r) * D_IN + k] : 0.f;
            s_b[r][kk] = (k < D_IN) ? W_ih[(size_t)(j0 + r) * D_IN + k] : 0.f;
        }
        __syncthreads();
        #pragma unroll
        for (int kk = 0; kk < 16; ++kk) {
            float a[4], b[4];
            #pragma unroll
            for (int r = 0; r < 4; ++r) a[r] = s_a[ty * 4 + r][kk];
            #pragma unroll
            for (int c = 0; c < 4; ++c) b[c] = s_b[tx * 4 + c][kk];
            #pragma unroll
            for (int r = 0; r < 4; ++r)
                #pragma unroll
                for (int c = 0; c < 4; ++c)
                    acc[r][c] += a[r] * b[c];
        }
        __syncthreads();
    }

    float bias[4];
    #pragma unroll
    for (int c = 0; c < 4; ++c) {
        int j = j0 + tx * 4 + c;
        bias[c] = b_ih[j] + b_hh[j];
    }
    #pragma unroll
    for (int r = 0; r < 4; ++r) {
        int t = t0 + ty * 4 + r;
        #pragma unroll
        for (int c = 0; c < 4; ++c) {
            xg[(size_t)t * G4 + j0 + tx * 4 + c] = acc[r][c] + bias[c];
        }
    }
}

// ---------------------------------------------------------------------------
// Phase 2: persistent sequential LSTM.
// 32 blocks x 512 threads (8 waves). Block g owns h[16g..16g+16) -> 64 rows.
// Wave w handles the 64-col slice [64w, 64w+64) for all 64 rows:
//   lane l -> row (j = l&15, gate = l>>4), cols 64w..64w+64.
// Each thread polls exactly ONE 8B self-validating message (tag<<32 | h_bits),
// stages it intra-wave into LDS (no barrier), computes a 64-FMA partial, and
// writes it to LDS. ONE lgkm-only barrier per step (no vmcnt drain!); wave 0
// then reduces 8 partials/row, applies gates, and publishes h via 16 coalesced
// agent-scope 8B stores. Waves 1..7 proceed directly to the next poll.
// ---------------------------------------------------------------------------
__global__ __launch_bounds__(512, 1) void lstm_seq(
    const float* __restrict__ W_hh, const float* __restrict__ xg,
    float* __restrict__ hs, u64* msg)
{
    const int tid  = threadIdx.x;        // 0..511
    const int g    = blockIdx.x;         // 0..31
    const int w    = tid >> 6;           // wave id = col chunk 0..7
    const int lane = tid & 63;
    const int j    = lane & 15;
    const int gate = lane >> 4;
    const int row  = gate * H_DIM + g * 16 + j;   // global W_hh row

    // This thread's 64 weights in registers.
    float4 wv[16];
    {
        const float4* wr = (const float4*)(W_hh + (size_t)row * H_DIM + w * 64);
        #pragma unroll
        for (int i = 0; i < 16; ++i) wv[i] = wr[i];
    }

    __shared__ float s_h[512];           // wave w stages+reads [64w,64w+64) only
    __shared__ float s_part[2][512];     // [t&1][w*64 + lane], double-buffered

    u64* slot0 = msg;
    u64* slot1 = msg + 512;

    float c_state = 0.f;                 // wave0: state for j=lane&15 (x4 replicated)

    for (int t = 0; t < T_STEPS; ++t) {
        const unsigned tagt = (unsigned)t;

        // Wave 0 prefetches x_gates (independent of h) before the spin.
        float xv = 0.f;
        if (w == 0) xv = xg[(size_t)t * G4 + row];

        // Poll own single message word: tag==t validates payload in-load.
        u64* rp = ((t & 1) ? slot1 : slot0) + tid;
        u64 u;
        for (;;) {
            u = __hip_atomic_load(rp, __ATOMIC_RELAXED, __HIP_MEMORY_SCOPE_AGENT);
            if ((unsigned)(u >> 32) == tagt) break;
        }

        // Intra-wave h staging: wave w only touches its own 64-word region.
        s_h[tid] = __uint_as_float((unsigned)u);
        // (compiler inserts the lgkmcnt wait before the dependent reads)

        // Matvec partial: 64 cols of this thread's row.
        const float4* hv = (const float4*)(s_h + w * 64);
        float acc = 0.f;
        #pragma unroll
        for (int i = 0; i < 16; ++i) {
            float4 h4 = hv[i];
            acc += wv[i].x * h4.x + wv[i].y * h4.y +
                   wv[i].z * h4.z + wv[i].w * h4.w;
        }
        s_part[t & 1][tid] = acc;

        // lgkm-only barrier: LDS writes visible, NO vmcnt drain (publish store
        // and in-flight polls stay in flight across it).
        asm volatile("s_waitcnt lgkmcnt(0)\n\ts_barrier" ::: "memory");

        if (w == 0) {
            // Reduce the 8 per-wave partials for this lane's row.
            const float* pp = &s_part[t & 1][0];
            float sum = xv;
            #pragma unroll
            for (int k = 0; k < 8; ++k) sum += pp[k * 64 + lane];

            // Gather the 4 gates of column j (rows j, j+16, j+32, j+48).
            float gi = __shfl(sum, j + 0,  64);
            float gf = __shfl(sum, j + 16, 64);
            float gg = __shfl(sum, j + 32, 64);
            float go = __shfl(sum, j + 48, 64);

            float iv = fast_sigmoid(gi);
            float fv = fast_sigmoid(gf);
            float ov = fast_sigmoid(go);
            float gv = fast_tanh(gg);
            c_state = fv * c_state + iv * gv;     // identical on the 4 gate-lanes
            float hn = ov * fast_tanh(c_state);

            if (lane < 16) {                      // j == lane here
                hs[(size_t)t * H_DIM + g * 16 + lane] = hn;
                u64 m = ((u64)(tagt + 1) << 32) | (u64)__float_as_uint(hn);
                u64* wp = (((t + 1) & 1) ? slot1 : slot0) + (g * 16 + lane);
                __hip_atomic_store(wp, m, __ATOMIC_RELAXED, __HIP_MEMORY_SCOPE_AGENT);
            }
        }
        // No end-of-loop barrier: s_h is intra-wave; s_part is double-buffered,
        // and its re-write at t+2 is gated by the barrier at t+1, which wave 0
        // only reaches after finishing its reads of s_part[t&1].
    }
}

// ---------------------------------------------------------------------------
// Phase 3: out = log_softmax(hs @ W_out^T + b_out)
// ---------------------------------------------------------------------------
__global__ __launch_bounds__(256) void out_softmax(
    const float* __restrict__ hs, const float* __restrict__ W_out,
    const float* __restrict__ b_out, float* __restrict__ out)
{
    const int tid = threadIdx.x;
    const int t0  = blockIdx.x * 16;

    __shared__ float s_w[257 * 33];
    __shared__ float s_hs[16 * 33];
    __shared__ float s_o[16 * 257];
    __shared__ float s_red[8];

    float acc[16] = {};
    float acc256 = 0.f;

    for (int k0 = 0; k0 < H_DIM; k0 += 32) {
        for (int idx = tid; idx < 257 * 32; idx += 256) {
            int row = idx >> 5, col = idx & 31;
            s_w[row * 33 + col] = W_out[(size_t)row * H_DIM + k0 + col];
        }
        for (int idx = tid; idx < 16 * 32; idx += 256) {
            int row = idx >> 5, col = idx & 31;
            s_hs[row * 33 + col] = hs[(size_t)(t0 + row) * H_DIM + k0 + col];
        }
        __syncthreads();
        #pragma unroll
        for (int kk = 0; kk < 32; ++kk) {
            float w = s_w[tid * 33 + kk];
            #pragma unroll
            for (int r = 0; r < 16; ++r)
                acc[r] += s_hs[r * 33 + kk] * w;
        }
        if (tid < 16) {
            #pragma unroll
            for (int kk = 0; kk < 32; ++kk)
                acc256 += s_w[256 * 33 + kk] * s_hs[tid * 33 + kk];
        }
        __syncthreads();
    }

    float bias_c = b_out[tid];
    #pragma unroll
    for (int r = 0; r < 16; ++r) s_o[r * 257 + tid] = acc[r] + bias_c;
    if (tid < 16) s_o[tid * 257 + 256] = acc256 + b_out[256];
    __syncthreads();

    const int lane = tid & 63, wid = tid >> 6;
    for (int r = 0; r < 16; ++r) {
        float v  = s_o[r * 257 + tid];
        float vx = (tid == 0) ? s_o[r * 257 + 256] : -INFINITY;
        float m = fmaxf(v, vx);
        #pragma unroll
        for (int off = 32; off > 0; off >>= 1) m = fmaxf(m, __shfl_xor(m, off, 64));
        if (lane == 0) s_red[wid] = m;
        __syncthreads();
        m = fmaxf(fmaxf(s_red[0], s_red[1]), fmaxf(s_red[2], s_red[3]));
        float e = expf(v - m) + ((tid == 0) ? expf(vx - m) : 0.f);
        #pragma unroll
        for (int off = 32; off > 0; off >>= 1) e += __shfl_xor(e, off, 64);
        if (lane == 0) s_red[4 + wid] = e;
        __syncthreads();
        float s = s_red[4] + s_red[5] + s_red[6] + s_red[7];
        float lg = logf(s) + m;
        out[(size_t)(t0 + r) * O_DIM + tid] = v - lg;
        if (tid == 0) out[(size_t)(t0 + r) * O_DIM + 256] = vx - lg;
    }
}

// ---------------------------------------------------------------------------
extern "C" void kernel_launch(void* const* d_in, const int* in_sizes, int n_in,
                              void* d_out, int out_size, void* d_ws, size_t ws_size,
                              hipStream_t stream) {
    (void)in_sizes; (void)n_in; (void)out_size; (void)ws_size;

    const float* stft  = (const float*)d_in[0];
    const float* W_ih  = (const float*)d_in[1];
    const float* W_hh  = (const float*)d_in[2];
    const float* b_ih  = (const float*)d_in[3];
    const float* b_hh  = (const float*)d_in[4];
    const float* W_out = (const float*)d_in[5];
    const float* b_out = (const float*)d_in[6];
    float* out = (float*)d_out;

    char* ws = (char*)d_ws;
    u64* msg  = (u64*)ws;
    float* xg = (float*)(ws + WS_XG_OFF);
    float* hs = (float*)(ws + WS_HS_OFF);

    // Zero both msg slots (ws is re-poisoned to 0xAA before every launch).
    // tag 0 + h 0 is exactly the t=0 initial state.
    (void)hipMemsetAsync(ws, 0, 8192, stream);

    xgate_gemm<<<dim3(G4 / 64, T_STEPS / 64), 256, 0, stream>>>(
        stft, W_ih, b_ih, b_hh, xg);
    lstm_seq<<<32, 512, 0, stream>>>(W_hh, xg, hs, msg);
    out_softmax<<<T_STEPS / 16, 256, 0, stream>>>(hs, W_out, b_out, out);
}